// Round 1
// baseline (179.835 us; speedup 1.0000x reference)
//
#include <hip/hip_runtime.h>
#include <math.h>

#define SELU_SCALE 1.0507009873554805f
#define SELU_ALPHA 1.6732632423543772f

constexpr int CIN  = 3;
constexpr int HH   = 32;
constexpr int WW   = 32;
constexpr int OUTF = 64;

// One block per image n. 256 threads: thread t owns output row h = t>>3,
// output cols w0..w0+3 where w0 = (t&7)*4  (i.e. 2 LPPool pairs).
__global__ __launch_bounds__(256, 2) void fused_conv_selu_pool(
    const float* __restrict__ x,          // (1024, 3, 32, 32)
    const float* __restrict__ weight,     // (27, 64)  k = c*9+ki*3+kj
    const float* __restrict__ bias,       // (64,)
    const float* __restrict__ scale_proj, // (3, 64)
    const float* __restrict__ scale_bias, // (64,)
    float* __restrict__ out)              // (1024, 64)
{
    const int n    = blockIdx.x;
    const int t    = threadIdx.x;
    const int lane = t & 63;
    const int wave = t >> 6;

    __shared__ float xs[CIN][34][34];   // zero-padded input tile, 13.9 KB
    __shared__ float red[4][OUTF];      // per-wave pooled partials
    __shared__ float credu[CIN][4];     // per-wave channel-sum partials

    // ---- zero the padded tile (borders matter) ----
    float* xsf = &xs[0][0][0];
    for (int i = t; i < CIN * 34 * 34; i += 256) xsf[i] = 0.f;
    __syncthreads();

    // ---- load x[n] into LDS interior + per-channel sums ----
    const float* xn = x + (size_t)n * (CIN * HH * WW);
    float cp0 = 0.f, cp1 = 0.f, cp2 = 0.f;
    for (int i = t; i < CIN * HH * WW; i += 256) {  // 12 iters, coalesced
        float v  = xn[i];
        int   c  = i >> 10;       // H*W = 1024
        int   hw = i & 1023;
        xs[c][(hw >> 5) + 1][(hw & 31) + 1] = v;
        // c is wave-uniform each iteration (256 | 1024) -> no divergence
        if (c == 0) cp0 += v; else if (c == 1) cp1 += v; else cp2 += v;
    }
    #pragma unroll
    for (int off = 32; off > 0; off >>= 1) {
        cp0 += __shfl_down(cp0, off);
        cp1 += __shfl_down(cp1, off);
        cp2 += __shfl_down(cp2, off);
    }
    if (lane == 0) { credu[0][wave] = cp0; credu[1][wave] = cp1; credu[2][wave] = cp2; }
    __syncthreads();   // covers xs interior writes + credu

    // ---- hoist this thread's input window into registers ----
    const int h  = t >> 3;          // 0..31
    const int w0 = (t & 7) << 2;    // 0,4,...,28
    float xr[CIN][3][6];
    #pragma unroll
    for (int c = 0; c < CIN; ++c)
        #pragma unroll
        for (int r = 0; r < 3; ++r)
            #pragma unroll
            for (int j = 0; j < 6; ++j)
                xr[c][r][j] = xs[c][h + r][w0 + j];

    // ---- conv + SELU + LPPool(p=2,k=2) accumulate per output channel ----
    float acc[OUTF];
    #pragma unroll 2
    for (int o = 0; o < OUTF; ++o) {
        const float b = bias[o];                 // uniform -> scalar load
        float s0 = b, s1 = b, s2 = b, s3 = b;
        #pragma unroll
        for (int c = 0; c < CIN; ++c)
            #pragma unroll
            for (int ki = 0; ki < 3; ++ki)
                #pragma unroll
                for (int kj = 0; kj < 3; ++kj) {
                    const float wv = weight[(c * 9 + ki * 3 + kj) * 64 + o]; // uniform
                    s0 = fmaf(xr[c][ki][kj + 0], wv, s0);
                    s1 = fmaf(xr[c][ki][kj + 1], wv, s1);
                    s2 = fmaf(xr[c][ki][kj + 2], wv, s2);
                    s3 = fmaf(xr[c][ki][kj + 3], wv, s3);
                }
        // SELU
        s0 = s0 > 0.f ? SELU_SCALE * s0 : SELU_SCALE * SELU_ALPHA * (__expf(s0) - 1.f);
        s1 = s1 > 0.f ? SELU_SCALE * s1 : SELU_SCALE * SELU_ALPHA * (__expf(s1) - 1.f);
        s2 = s2 > 0.f ? SELU_SCALE * s2 : SELU_SCALE * SELU_ALPHA * (__expf(s2) - 1.f);
        s3 = s3 > 0.f ? SELU_SCALE * s3 : SELU_SCALE * SELU_ALPHA * (__expf(s3) - 1.f);
        // LPPool over w pairs
        const float p0 = sqrtf(s0 * s0 + s1 * s1);
        const float p1 = sqrtf(s2 * s2 + s3 * s3);
        acc[o] = p0 + p1;
    }

    // ---- reduce pooled sums across the block ----
    #pragma unroll 4
    for (int o = 0; o < OUTF; ++o) {
        float r = acc[o];
        #pragma unroll
        for (int off = 32; off > 0; off >>= 1) r += __shfl_down(r, off);
        if (lane == 0) red[wave][o] = r;
    }
    __syncthreads();

    // ---- gate + store ----
    if (t < OUTF) {
        const float s    = red[0][t] + red[1][t] + red[2][t] + red[3][t];
        const float mean = s * (1.f / 512.f);   // 32*16 pooled elements
        float g = scale_bias[t];
        #pragma unroll
        for (int c = 0; c < CIN; ++c) {
            const float cs = (credu[c][0] + credu[c][1] + credu[c][2] + credu[c][3])
                             * (1.f / 1024.f);
            g = fmaf(cs, scale_proj[c * 64 + t], g);
        }
        g = 1.f / (1.f + __expf(-g));
        out[(size_t)n * OUTF + t] = mean * g;
    }
}

extern "C" void kernel_launch(void* const* d_in, const int* in_sizes, int n_in,
                              void* d_out, int out_size, void* d_ws, size_t ws_size,
                              hipStream_t stream) {
    const float* x          = (const float*)d_in[0];
    const float* weight     = (const float*)d_in[1];
    const float* bias       = (const float*)d_in[2];
    const float* scale_proj = (const float*)d_in[3];
    const float* scale_bias = (const float*)d_in[4];
    float* out = (float*)d_out;

    fused_conv_selu_pool<<<1024, 256, 0, stream>>>(x, weight, bias,
                                                   scale_proj, scale_bias, out);
}

// Round 2
// 137.975 us; speedup vs baseline: 1.3034x; 1.3034x over previous
//
#include <hip/hip_runtime.h>
#include <math.h>

#define SELU_SCALE 1.0507009873554805f
#define SELU_ALPHA 1.6732632423543772f

constexpr int CIN  = 3;
constexpr int HH   = 32;
constexpr int WW   = 32;
constexpr int OUTF = 64;

// One block per image n. 256 threads: thread t owns output row h = t>>3,
// output cols w0..w0+3 (= 2 LPPool pairs). Per output channel we compute the
// 4 conv outputs from a register-resident 3x3x6 window, apply SELU+pool,
// and wave-reduce immediately — NO per-thread acc array (round-1 bug: a
// dynamically-indexed acc[64] in a partially-unrolled loop went to scratch:
// 65 MB of HBM writes, 127 us).
__global__ __launch_bounds__(256, 4) void fused_conv_selu_pool(
    const float* __restrict__ x,          // (1024, 3, 32, 32)
    const float* __restrict__ weight,     // (27, 64)  k = c*9+ki*3+kj
    const float* __restrict__ bias,       // (64,)
    const float* __restrict__ scale_proj, // (3, 64)
    const float* __restrict__ scale_bias, // (64,)
    float* __restrict__ out)              // (1024, 64)
{
    const int n    = blockIdx.x;
    const int t    = threadIdx.x;
    const int lane = t & 63;
    const int wave = t >> 6;

    __shared__ float xs[CIN][34][34];   // zero-padded input tile, 13.9 KB
    __shared__ float red[4][OUTF];      // per-wave pooled partials
    __shared__ float credu[CIN][4];     // per-wave channel-sum partials

    // ---- zero the padded tile (borders matter) ----
    float* xsf = &xs[0][0][0];
    for (int i = t; i < CIN * 34 * 34; i += 256) xsf[i] = 0.f;
    __syncthreads();

    // ---- load x[n] into LDS interior + per-channel sums ----
    const float* xn = x + (size_t)n * (CIN * HH * WW);
    float cp0 = 0.f, cp1 = 0.f, cp2 = 0.f;
    for (int i = t; i < CIN * HH * WW; i += 256) {  // 12 iters, coalesced
        float v  = xn[i];
        int   c  = i >> 10;       // H*W = 1024
        int   hw = i & 1023;
        xs[c][(hw >> 5) + 1][(hw & 31) + 1] = v;
        // c is wave-uniform each iteration (256 | 1024) -> no divergence
        if (c == 0) cp0 += v; else if (c == 1) cp1 += v; else cp2 += v;
    }
    #pragma unroll
    for (int off = 32; off > 0; off >>= 1) {
        cp0 += __shfl_down(cp0, off);
        cp1 += __shfl_down(cp1, off);
        cp2 += __shfl_down(cp2, off);
    }
    if (lane == 0) { credu[0][wave] = cp0; credu[1][wave] = cp1; credu[2][wave] = cp2; }
    __syncthreads();   // covers xs interior writes + credu

    // ---- hoist this thread's input window into registers (54 VGPRs) ----
    const int h  = t >> 3;          // 0..31
    const int w0 = (t & 7) << 2;    // 0,4,...,28
    float xr[CIN][3][6];
    #pragma unroll
    for (int c = 0; c < CIN; ++c)
        #pragma unroll
        for (int r = 0; r < 3; ++r)
            #pragma unroll
            for (int j = 0; j < 6; ++j)
                xr[c][r][j] = xs[c][h + r][w0 + j];

    // ---- conv + SELU + LPPool + in-loop wave reduction ----
    // SELU_SCALE is hoisted: p = sqrt((S*a0)^2 + (S*a1)^2) = S*sqrt(a0^2+a1^2),
    // and pooled-mean is linear in S -> apply once at the end.
    #pragma unroll 2
    for (int o = 0; o < OUTF; ++o) {
        const float b = bias[o];                 // wave-uniform -> scalar load
        float s0 = b, s1 = b, s2 = b, s3 = b;
        #pragma unroll
        for (int k = 0; k < 27; ++k) {           // k -> (c,ki,kj) compile-time
            const int c  = k / 9;
            const int ki = (k % 9) / 3;
            const int kj = k % 3;
            const float wv = weight[k * 64 + o]; // wave-uniform -> scalar load
            s0 = fmaf(xr[c][ki][kj + 0], wv, s0);
            s1 = fmaf(xr[c][ki][kj + 1], wv, s1);
            s2 = fmaf(xr[c][ki][kj + 2], wv, s2);
            s3 = fmaf(xr[c][ki][kj + 3], wv, s3);
        }
        // SELU without the outer scale
        s0 = s0 > 0.f ? s0 : SELU_ALPHA * (__expf(s0) - 1.f);
        s1 = s1 > 0.f ? s1 : SELU_ALPHA * (__expf(s1) - 1.f);
        s2 = s2 > 0.f ? s2 : SELU_ALPHA * (__expf(s2) - 1.f);
        s3 = s3 > 0.f ? s3 : SELU_ALPHA * (__expf(s3) - 1.f);
        // LPPool over the two w-pairs, then wave-reduce this channel now
        float r = sqrtf(s0 * s0 + s1 * s1) + sqrtf(s2 * s2 + s3 * s3);
        #pragma unroll
        for (int off = 32; off > 0; off >>= 1) r += __shfl_down(r, off);
        if (lane == 0) red[wave][o] = r;
    }
    __syncthreads();

    // ---- gate + store ----
    if (t < OUTF) {
        const float s    = red[0][t] + red[1][t] + red[2][t] + red[3][t];
        const float mean = s * (SELU_SCALE / 512.f);   // 32*16 pooled elems
        float g = scale_bias[t];
        #pragma unroll
        for (int c = 0; c < CIN; ++c) {
            const float cs = (credu[c][0] + credu[c][1] + credu[c][2] + credu[c][3])
                             * (1.f / 1024.f);
            g = fmaf(cs, scale_proj[c * 64 + t], g);
        }
        g = 1.f / (1.f + __expf(-g));
        out[(size_t)n * OUTF + t] = mean * g;
    }
}

extern "C" void kernel_launch(void* const* d_in, const int* in_sizes, int n_in,
                              void* d_out, int out_size, void* d_ws, size_t ws_size,
                              hipStream_t stream) {
    const float* x          = (const float*)d_in[0];
    const float* weight     = (const float*)d_in[1];
    const float* bias       = (const float*)d_in[2];
    const float* scale_proj = (const float*)d_in[3];
    const float* scale_bias = (const float*)d_in[4];
    float* out = (float*)d_out;

    fused_conv_selu_pool<<<1024, 256, 0, stream>>>(x, weight, bias,
                                                   scale_proj, scale_bias, out);
}

// Round 4
// 121.891 us; speedup vs baseline: 1.4754x; 1.1320x over previous
//
#include <hip/hip_runtime.h>
#include <math.h>

#define SELU_SCALE 1.0507009873554805f
#define SELU_ALPHA 1.6732632423543772f

constexpr int CIN  = 3;
constexpr int HH   = 32;
constexpr int WW   = 32;
constexpr int OUTF = 64;

// Full-wave (64-lane) sum reduction using DPP row ops — pure VALU, no LDS
// pipe (round-2 lesson: __shfl_down => ds_bpermute, 384 dependent LDS ops
// per thread => 35% VALU idle on lgkm waits). DPP controls MUST be
// compile-time constants -> template parameters (round-3 compile fix).
template <int CTRL, int ROW_MASK>
__device__ __forceinline__ float dpp_add(float v) {
    int sh = __builtin_amdgcn_update_dpp(0, __float_as_int(v),
                                         CTRL, ROW_MASK, 0xf, false);
    return v + __int_as_float(sh);
}
__device__ __forceinline__ float wave64_sum(float v) {
    v = dpp_add<0x111, 0xf>(v);  // row_shr:1
    v = dpp_add<0x112, 0xf>(v);  // row_shr:2
    v = dpp_add<0x114, 0xf>(v);  // row_shr:4
    v = dpp_add<0x118, 0xf>(v);  // row_shr:8
    v = dpp_add<0x142, 0xa>(v);  // row_bcast:15 -> rows 1,3
    v = dpp_add<0x143, 0xc>(v);  // row_bcast:31 -> rows 2,3
    return v;                    // lane 63 = full 64-lane sum
}

// One block per image n. 256 threads: thread t owns output row h = t>>3,
// output cols w0..w0+3 (= 2 LPPool pairs). Per output channel: 4 conv
// outputs from a register-resident 3x3x6 window, SELU+pool, DPP wave-reduce.
__global__ __launch_bounds__(256, 4) void fused_conv_selu_pool(
    const float* __restrict__ x,          // (1024, 3, 32, 32)
    const float* __restrict__ weight,     // (27, 64)  k = c*9+ki*3+kj
    const float* __restrict__ bias,       // (64,)
    const float* __restrict__ scale_proj, // (3, 64)
    const float* __restrict__ scale_bias, // (64,)
    float* __restrict__ out)              // (1024, 64)
{
    const int n    = blockIdx.x;
    const int t    = threadIdx.x;
    const int lane = t & 63;
    const int wave = t >> 6;

    __shared__ float xs[CIN][34][34];   // zero-padded input tile, 13.9 KB
    __shared__ float red[4][OUTF];      // per-wave pooled partials
    __shared__ float credu[CIN][4];     // per-wave channel-sum partials

    // ---- zero the padded tile (borders matter) ----
    float* xsf = &xs[0][0][0];
    for (int i = t; i < CIN * 34 * 34; i += 256) xsf[i] = 0.f;
    __syncthreads();

    // ---- load x[n] into LDS interior + per-channel sums ----
    const float* xn = x + (size_t)n * (CIN * HH * WW);
    float cp0 = 0.f, cp1 = 0.f, cp2 = 0.f;
    for (int i = t; i < CIN * HH * WW; i += 256) {  // 12 iters, coalesced
        float v  = xn[i];
        int   c  = i >> 10;       // H*W = 1024
        int   hw = i & 1023;
        xs[c][(hw >> 5) + 1][(hw & 31) + 1] = v;
        // c is wave-uniform each iteration (256 | 1024) -> no divergence
        if (c == 0) cp0 += v; else if (c == 1) cp1 += v; else cp2 += v;
    }
    cp0 = wave64_sum(cp0);
    cp1 = wave64_sum(cp1);
    cp2 = wave64_sum(cp2);
    if (lane == 63) { credu[0][wave] = cp0; credu[1][wave] = cp1; credu[2][wave] = cp2; }
    __syncthreads();   // covers xs interior writes + credu

    // ---- hoist this thread's input window into registers (54 VGPRs) ----
    const int h  = t >> 3;          // 0..31
    const int w0 = (t & 7) << 2;    // 0,4,...,28
    float xr[CIN][3][6];
    #pragma unroll
    for (int c = 0; c < CIN; ++c)
        #pragma unroll
        for (int r = 0; r < 3; ++r)
            #pragma unroll
            for (int j = 0; j < 6; ++j)
                xr[c][r][j] = xs[c][h + r][w0 + j];

    // ---- conv + SELU + LPPool + in-loop DPP wave reduction ----
    // SELU_SCALE hoisted: it commutes through the 2-norm pool and the mean.
    #pragma unroll 4
    for (int o = 0; o < OUTF; ++o) {
        const float b = bias[o];                 // wave-uniform -> scalar load
        float s0 = b, s1 = b, s2 = b, s3 = b;
        #pragma unroll
        for (int k = 0; k < 27; ++k) {           // k -> (c,ki,kj) compile-time
            const int c  = k / 9;
            const int ki = (k % 9) / 3;
            const int kj = k % 3;
            const float wv = weight[k * 64 + o]; // wave-uniform -> scalar load
            s0 = fmaf(xr[c][ki][kj + 0], wv, s0);
            s1 = fmaf(xr[c][ki][kj + 1], wv, s1);
            s2 = fmaf(xr[c][ki][kj + 2], wv, s2);
            s3 = fmaf(xr[c][ki][kj + 3], wv, s3);
        }
        // SELU without the outer scale
        s0 = s0 > 0.f ? s0 : SELU_ALPHA * (__expf(s0) - 1.f);
        s1 = s1 > 0.f ? s1 : SELU_ALPHA * (__expf(s1) - 1.f);
        s2 = s2 > 0.f ? s2 : SELU_ALPHA * (__expf(s2) - 1.f);
        s3 = s3 > 0.f ? s3 : SELU_ALPHA * (__expf(s3) - 1.f);
        // LPPool over the two w-pairs, then DPP-reduce this channel now
        float r = __builtin_amdgcn_sqrtf(fmaf(s0, s0, s1 * s1))
                + __builtin_amdgcn_sqrtf(fmaf(s2, s2, s3 * s3));
        r = wave64_sum(r);
        if (lane == 63) red[wave][o] = r;
    }
    __syncthreads();

    // ---- gate + store ----
    if (t < OUTF) {
        const float s    = red[0][t] + red[1][t] + red[2][t] + red[3][t];
        const float mean = s * (SELU_SCALE / 512.f);   // 32*16 pooled elems
        float g = scale_bias[t];
        #pragma unroll
        for (int c = 0; c < CIN; ++c) {
            const float cs = (credu[c][0] + credu[c][1] + credu[c][2] + credu[c][3])
                             * (1.f / 1024.f);
            g = fmaf(cs, scale_proj[c * 64 + t], g);
        }
        g = 1.f / (1.f + __expf(-g));
        out[(size_t)n * OUTF + t] = mean * g;
    }
}

extern "C" void kernel_launch(void* const* d_in, const int* in_sizes, int n_in,
                              void* d_out, int out_size, void* d_ws, size_t ws_size,
                              hipStream_t stream) {
    const float* x          = (const float*)d_in[0];
    const float* weight     = (const float*)d_in[1];
    const float* bias       = (const float*)d_in[2];
    const float* scale_proj = (const float*)d_in[3];
    const float* scale_bias = (const float*)d_in[4];
    float* out = (float*)d_out;

    fused_conv_selu_pool<<<1024, 256, 0, stream>>>(x, weight, bias,
                                                   scale_proj, scale_bias, out);
}